// Round 1
// baseline (1160.559 us; speedup 1.0000x reference)
//
#include <hip/hip_runtime.h>

#define BB 8
#define C 64
#define HH 128
#define WW 128
#define HW (HH*WW)

// ---------------------------------------------------------------------------
// Dense 3x3 conv, pad 1. Each block: 16x16 spatial tile, 16 output channels.
// Input channel tiles staged in LDS; weights fetched via thread-uniform index
// (compiler emits s_load, FMA takes SGPR operand -> no LDS/VMEM weight traffic).
// ---------------------------------------------------------------------------
template<bool RESIDUAL>
__global__ __launch_bounds__(256) void conv3x3_kernel(
    const float* __restrict__ in,    // [B,C,H,W]
    const float* __restrict__ wgt,   // [C,C,3,3]
    const float* __restrict__ bias,  // [C]
    const float* __restrict__ res,   // [B,C,H,W] (only if RESIDUAL)
    float* __restrict__ out)         // [B,C,H,W]
{
    __shared__ float tile[18*18];
    const int tx = threadIdx.x & 15;
    const int ty = threadIdx.x >> 4;
    const int b   = blockIdx.z >> 2;
    const int co0 = (blockIdx.z & 3) * 16;
    const int w0p = blockIdx.x * 16;
    const int h0p = blockIdx.y * 16;
    const int hh = h0p + ty, ww = w0p + tx;

    float acc[16];
#pragma unroll
    for (int i = 0; i < 16; ++i) acc[i] = 0.f;

    for (int ci = 0; ci < C; ++ci) {
        __syncthreads();
        const float* src = in + (size_t)(b*C + ci)*HW;
        for (int idx = threadIdx.x; idx < 18*18; idx += 256) {
            int r = idx / 18, c = idx - r*18;
            int gh = h0p + r - 1, gw = w0p + c - 1;
            float v = 0.f;
            if ((unsigned)gh < HH && (unsigned)gw < WW) v = src[gh*WW + gw];
            tile[idx] = v;
        }
        __syncthreads();
        float p[9];
#pragma unroll
        for (int kh = 0; kh < 3; ++kh)
#pragma unroll
            for (int kw = 0; kw < 3; ++kw)
                p[kh*3+kw] = tile[(ty+kh)*18 + (tx+kw)];
        const float* wp = wgt + (size_t)(co0*C + ci)*9;   // + i*C*9 + k
#pragma unroll
        for (int i = 0; i < 16; ++i) {
#pragma unroll
            for (int k = 0; k < 9; ++k)
                acc[i] = fmaf(wp[i*C*9 + k], p[k], acc[i]);
        }
    }

    float* dst = out + (size_t)(b*C + co0)*HW + hh*WW + ww;
    const float* rp = res + (size_t)(b*C + co0)*HW + hh*WW + ww;
#pragma unroll
    for (int i = 0; i < 16; ++i) {
        float v = acc[i] + bias[co0 + i];
        if (RESIDUAL) v += rp[i*HW];
        dst[i*HW] = v;
    }
}

// ---------------------------------------------------------------------------
// Per-(b,c) spatial mean of x0 -> m[b*C+c]
// ---------------------------------------------------------------------------
__global__ __launch_bounds__(256) void mean_kernel(
    const float* __restrict__ x0, float* __restrict__ m)
{
    const int bc = blockIdx.x;            // 0..511
    const float* src = x0 + (size_t)bc * HW;
    float s = 0.f;
    for (int i = threadIdx.x; i < HW; i += 256) s += src[i];
#pragma unroll
    for (int off = 32; off > 0; off >>= 1) s += __shfl_down(s, off);
    __shared__ float red[4];
    const int lane = threadIdx.x & 63, wv = threadIdx.x >> 6;
    if (lane == 0) red[wv] = s;
    __syncthreads();
    if (threadIdx.x == 0)
        m[bc] = (red[0] + red[1] + red[2] + red[3]) * (1.f/HW);
}

// ---------------------------------------------------------------------------
// Fused: depthwise 3x3 + ECA attn -> out[64] (regs) ; fil = w3 @ out + b3 ;
// y = leaky( sum_j fil[c,j] * x0patch[c,j] )
// ---------------------------------------------------------------------------
__global__ __launch_bounds__(256) void fused_kernel(
    const float* __restrict__ x0,
    const float* __restrict__ w1, const float* __restrict__ b1,
    const float* __restrict__ w2, const float* __restrict__ b2,
    const float* __restrict__ w3, const float* __restrict__ b3,
    const float* __restrict__ m,  // [B*C]
    float* __restrict__ y)
{
    __shared__ float tile[18*18];
    const int tx = threadIdx.x & 15;
    const int ty = threadIdx.x >> 4;
    const int b   = blockIdx.z;
    const int w0p = blockIdx.x * 16;
    const int h0p = blockIdx.y * 16;

    const float w2a = w2[0], w2b = w2[1], w2c = w2[2], b2v = b2[0];

    float outv[C];

    // ---- phase 1: out[c] = depthwise(x0)[c] + b1[c] + attn[b,c] ----
#pragma unroll
    for (int c = 0; c < C; ++c) {
        __syncthreads();
        const float* src = x0 + (size_t)(b*C + c)*HW;
        for (int idx = threadIdx.x; idx < 18*18; idx += 256) {
            int r = idx / 18, cc = idx - r*18;
            int gh = h0p + r - 1, gw = w0p + cc - 1;
            float v = 0.f;
            if ((unsigned)gh < HH && (unsigned)gw < WW) v = src[gh*WW + gw];
            tile[idx] = v;
        }
        __syncthreads();
        float dw = 0.f;
#pragma unroll
        for (int kh = 0; kh < 3; ++kh)
#pragma unroll
            for (int kw = 0; kw < 3; ++kw)
                dw = fmaf(w1[c*9 + kh*3 + kw], tile[(ty+kh)*18 + (tx+kw)], dw);
        const float mc = m[b*C + c];
        const float mp = (c > 0)   ? m[b*C + c - 1] : 0.f;
        const float mn = (c < C-1) ? m[b*C + c + 1] : 0.f;
        const float att = fmaf(w2a, mp, fmaf(w2b, mc, fmaf(w2c, mn, b2v)));
        outv[c] = dw + b1[c] + att;
    }

    // ---- phase 2: dynamic filters + dynamic conv + leaky ----
    for (int c = 0; c < C; ++c) {        // rolled: c never indexes outv
        __syncthreads();
        const float* src = x0 + (size_t)(b*C + c)*HW;
        for (int idx = threadIdx.x; idx < 18*18; idx += 256) {
            int r = idx / 18, cc = idx - r*18;
            int gh = h0p + r - 1, gw = w0p + cc - 1;
            float v = 0.f;
            if ((unsigned)gh < HH && (unsigned)gw < WW) v = src[gh*WW + gw];
            tile[idx] = v;
        }
        __syncthreads();
        float p[9];
#pragma unroll
        for (int kh = 0; kh < 3; ++kh)
#pragma unroll
            for (int kw = 0; kw < 3; ++kw)
                p[kh*3+kw] = tile[(ty+kh)*18 + (tx+kw)];

        float yc = 0.f;
#pragma unroll
        for (int j = 0; j < 9; ++j) {
            const float* wrow = w3 + (size_t)(c*9 + j)*C;   // uniform -> s_load
            float f = b3[c*9 + j];
#pragma unroll
            for (int ci = 0; ci < C; ++ci)
                f = fmaf(wrow[ci], outv[ci], f);
            yc = fmaf(f, p[j], yc);
        }
        yc = (yc >= 0.f) ? yc : 0.2f * yc;
        y[(size_t)(b*C + c)*HW + (h0p+ty)*WW + (w0p+tx)] = yc;
    }
}

extern "C" void kernel_launch(void* const* d_in, const int* in_sizes, int n_in,
                              void* d_out, int out_size, void* d_ws, size_t ws_size,
                              hipStream_t stream) {
    const float* x  = (const float*)d_in[0];
    const float* w0 = (const float*)d_in[1];
    const float* b0 = (const float*)d_in[2];
    const float* w1 = (const float*)d_in[3];
    const float* b1 = (const float*)d_in[4];
    const float* w2 = (const float*)d_in[5];
    const float* b2 = (const float*)d_in[6];
    const float* w3 = (const float*)d_in[7];
    const float* b3 = (const float*)d_in[8];
    const float* wf = (const float*)d_in[9];
    const float* bf = (const float*)d_in[10];
    float* out = (float*)d_out;

    float* x0 = (float*)d_ws;                       // [B,C,H,W]
    float* y  = x0 + (size_t)BB*C*HW;               // [B,C,H,W]
    float* m  = y  + (size_t)BB*C*HW;               // [B*C]

    dim3 blk(256);
    dim3 gridc(WW/16, HH/16, BB*4);
    conv3x3_kernel<false><<<gridc, blk, 0, stream>>>(x, w0, b0, x /*unused*/, x0);
    mean_kernel<<<dim3(BB*C), blk, 0, stream>>>(x0, m);
    fused_kernel<<<dim3(WW/16, HH/16, BB), blk, 0, stream>>>(
        x0, w1, b1, w2, b2, w3, b3, m, y);
    conv3x3_kernel<true><<<gridc, blk, 0, stream>>>(y, wf, bf, x, out);
}

// Round 2
// 867.045 us; speedup vs baseline: 1.3385x; 1.3385x over previous
//
#include <hip/hip_runtime.h>

#define BB 8
#define C 64
#define HH 128
#define WW 128
#define HW (HH*WW)

// ---------------------------------------------------------------------------
// Dense 3x3 conv, pad 1. 16x16 pixel tile, 16 output channels per block.
// 16 input channels staged per LDS round -> 8 barriers total (was 128).
// ---------------------------------------------------------------------------
template<bool RESIDUAL>
__global__ __launch_bounds__(256) void conv3x3_kernel(
    const float* __restrict__ in,    // [B,C,H,W]
    const float* __restrict__ wgt,   // [C,C,3,3]
    const float* __restrict__ bias,  // [C]
    const float* __restrict__ res,   // [B,C,H,W] (only if RESIDUAL)
    float* __restrict__ out)         // [B,C,H,W]
{
    __shared__ float tile[16*324];   // 16 ch x 18x18, 20.7 KB
    const int tx = threadIdx.x & 15;
    const int ty = threadIdx.x >> 4;
    const int b   = blockIdx.z >> 2;
    const int co0 = (blockIdx.z & 3) * 16;
    const int w0p = blockIdx.x * 16;
    const int h0p = blockIdx.y * 16;

    float acc[16];
#pragma unroll
    for (int i = 0; i < 16; ++i) acc[i] = 0.f;

    for (int chunk = 0; chunk < 4; ++chunk) {
        __syncthreads();
        const float* srcb = in + (size_t)(b*C + chunk*16)*HW;
        for (int t = threadIdx.x; t < 16*324; t += 256) {
            int ch = t / 324;
            int idx = t - ch*324;
            int r = idx / 18, cc = idx - r*18;
            int gh = h0p + r - 1, gw = w0p + cc - 1;
            float v = 0.f;
            if ((unsigned)gh < HH && (unsigned)gw < WW)
                v = srcb[ch*HW + gh*WW + gw];
            tile[t] = v;
        }
        __syncthreads();
        for (int cl = 0; cl < 16; ++cl) {            // rolled: small I$ body
            float p[9];
#pragma unroll
            for (int kh = 0; kh < 3; ++kh)
#pragma unroll
                for (int kw = 0; kw < 3; ++kw)
                    p[kh*3+kw] = tile[cl*324 + (ty+kh)*18 + tx+kw];
            const float* wp = wgt + ((size_t)co0*C + chunk*16 + cl)*9;  // uniform
#pragma unroll
            for (int oc = 0; oc < 16; ++oc)
#pragma unroll
                for (int k = 0; k < 9; ++k)
                    acc[oc] = fmaf(wp[oc*C*9 + k], p[k], acc[oc]);
        }
    }

    const int hh = h0p + ty, ww = w0p + tx;
    float* dst = out + (size_t)(b*C + co0)*HW + hh*WW + ww;
    const float* rp = res + (size_t)(b*C + co0)*HW + hh*WW + ww;
#pragma unroll
    for (int i = 0; i < 16; ++i) {
        float v = acc[i] + bias[co0 + i];
        if (RESIDUAL) v += rp[i*HW];
        dst[i*HW] = v;
    }
}

// ---------------------------------------------------------------------------
// Per-(b,c) spatial mean of x0 -> m[b*C+c]
// ---------------------------------------------------------------------------
__global__ __launch_bounds__(256) void mean_kernel(
    const float* __restrict__ x0, float* __restrict__ m)
{
    const int bc = blockIdx.x;            // 0..511
    const float* src = x0 + (size_t)bc * HW;
    float s = 0.f;
    for (int i = threadIdx.x; i < HW; i += 256) s += src[i];
#pragma unroll
    for (int off = 32; off > 0; off >>= 1) s += __shfl_down(s, off);
    __shared__ float red[4];
    const int lane = threadIdx.x & 63, wv = threadIdx.x >> 6;
    if (lane == 0) red[wv] = s;
    __syncthreads();
    if (threadIdx.x == 0)
        m[bc] = (red[0] + red[1] + red[2] + red[3]) * (1.f/HW);
}

// ---------------------------------------------------------------------------
// Fused: depthwise 3x3 + ECA attn -> outv[64] in regs ; fil = w3 @ outv + b3 ;
// y = leaky( sum_j fil[c,j] * x0patch[c,j] ).
// 32 channels staged per LDS round (41.5 KB); 3 stagings, 6 barriers total.
// Phase-2 inner product uses 9 parallel accumulator chains (ILP 9).
// ---------------------------------------------------------------------------
__global__ __launch_bounds__(256) void fused_kernel(
    const float* __restrict__ x0,
    const float* __restrict__ w1, const float* __restrict__ b1,
    const float* __restrict__ w2, const float* __restrict__ b2,
    const float* __restrict__ w3, const float* __restrict__ b3,
    const float* __restrict__ m,  // [B*C]
    float* __restrict__ y)
{
    __shared__ float tile[32*324];   // 32 ch x 18x18, 41.5 KB
    const int tx = threadIdx.x & 15;
    const int ty = threadIdx.x >> 4;
    const int b   = blockIdx.z;
    const int w0p = blockIdx.x * 16;
    const int h0p = blockIdx.y * 16;

    const float w2a = w2[0], w2b = w2[1], w2c = w2[2], b2v = b2[0];

    auto stage = [&](int chunk) {
        __syncthreads();
        const float* srcb = x0 + (size_t)(b*C + chunk*32)*HW;
        for (int t = threadIdx.x; t < 32*324; t += 256) {
            int ch = t / 324;
            int idx = t - ch*324;
            int r = idx / 18, cc = idx - r*18;
            int gh = h0p + r - 1, gw = w0p + cc - 1;
            float v = 0.f;
            if ((unsigned)gh < HH && (unsigned)gw < WW)
                v = srcb[ch*HW + gh*WW + gw];
            tile[t] = v;
        }
        __syncthreads();
    };

    float outv[C];

    auto phase1 = [&](int cl, int c) {   // c is a compile-time literal at each call
        float dw = 0.f;
#pragma unroll
        for (int kh = 0; kh < 3; ++kh)
#pragma unroll
            for (int kw = 0; kw < 3; ++kw)
                dw = fmaf(w1[c*9 + kh*3 + kw], tile[cl*324 + (ty+kh)*18 + tx+kw], dw);
        const float mc = m[b*C + c];
        const float mp = (c > 0)   ? m[b*C + c - 1] : 0.f;
        const float mn = (c < C-1) ? m[b*C + c + 1] : 0.f;
        outv[c] = dw + b1[c] + fmaf(w2a, mp, fmaf(w2b, mc, fmaf(w2c, mn, b2v)));
    };

    auto phase2_range = [&](int cbase) {  // processes channels [cbase, cbase+32)
        for (int cl = 0; cl < 32; ++cl) {            // rolled: small I$ body
            const int c = cbase + cl;
            float p[9];
#pragma unroll
            for (int kh = 0; kh < 3; ++kh)
#pragma unroll
                for (int kw = 0; kw < 3; ++kw)
                    p[kh*3+kw] = tile[cl*324 + (ty+kh)*18 + tx+kw];
            const float* w3p = w3 + (size_t)c*9*C;   // uniform, contiguous 2304B
            float f[9];
#pragma unroll
            for (int j = 0; j < 9; ++j) f[j] = b3[c*9 + j];
#pragma unroll
            for (int ci = 0; ci < C; ++ci)           // 9 independent chains
#pragma unroll
                for (int j = 0; j < 9; ++j)
                    f[j] = fmaf(w3p[j*C + ci], outv[ci], f[j]);
            float yc = 0.f;
#pragma unroll
            for (int j = 0; j < 9; ++j) yc = fmaf(f[j], p[j], yc);
            yc = (yc >= 0.f) ? yc : 0.2f * yc;
            y[(size_t)(b*C + c)*HW + (h0p+ty)*WW + (w0p+tx)] = yc;
        }
    };

    // phase 1: chunk 0 then chunk 1
    stage(0);
#pragma unroll
    for (int cl = 0; cl < 32; ++cl) phase1(cl, cl);
    stage(1);
#pragma unroll
    for (int cl = 0; cl < 32; ++cl) phase1(cl, 32 + cl);

    // phase 2: chunk 1 tiles are still resident -> do them first (saves a staging)
    phase2_range(32);
    stage(0);
    phase2_range(0);
}

extern "C" void kernel_launch(void* const* d_in, const int* in_sizes, int n_in,
                              void* d_out, int out_size, void* d_ws, size_t ws_size,
                              hipStream_t stream) {
    const float* x  = (const float*)d_in[0];
    const float* w0 = (const float*)d_in[1];
    const float* b0 = (const float*)d_in[2];
    const float* w1 = (const float*)d_in[3];
    const float* b1 = (const float*)d_in[4];
    const float* w2 = (const float*)d_in[5];
    const float* b2 = (const float*)d_in[6];
    const float* w3 = (const float*)d_in[7];
    const float* b3 = (const float*)d_in[8];
    const float* wf = (const float*)d_in[9];
    const float* bf = (const float*)d_in[10];
    float* out = (float*)d_out;

    float* x0 = (float*)d_ws;                       // [B,C,H,W]
    float* y  = x0 + (size_t)BB*C*HW;               // [B,C,H,W]
    float* m  = y  + (size_t)BB*C*HW;               // [B*C]

    dim3 blk(256);
    dim3 gridc(WW/16, HH/16, BB*4);
    conv3x3_kernel<false><<<gridc, blk, 0, stream>>>(x, w0, b0, x /*unused*/, x0);
    mean_kernel<<<dim3(BB*C), blk, 0, stream>>>(x0, m);
    fused_kernel<<<dim3(WW/16, HH/16, BB), blk, 0, stream>>>(
        x0, w1, b1, w2, b2, w3, b3, m, y);
    conv3x3_kernel<true><<<gridc, blk, 0, stream>>>(y, wf, bf, x, out);
}

// Round 3
// 542.625 us; speedup vs baseline: 2.1388x; 1.5979x over previous
//
#include <hip/hip_runtime.h>

#define BB 8
#define C 64
#define HH 128
#define WW 128
#define HW (HH*WW)

#define TS 72        // LDS channel stride (ushorts): 144B rows -> 16B aligned, bank-uniform
#define NPX 324      // 18*18 halo tile pixels

typedef __attribute__((ext_vector_type(8))) short short8;
typedef __attribute__((ext_vector_type(4))) float f32x4;

__device__ inline unsigned short f2bf(float f) {
    union { float f; unsigned u; } v; v.f = f;
    unsigned r = v.u + 0x7fff + ((v.u >> 16) & 1);   // RNE
    return (unsigned short)(r >> 16);
}
__device__ inline float bf2f(unsigned short h) {
    union { unsigned u; float f; } v; v.u = ((unsigned)h) << 16;
    return v.f;
}

// ---------------------------------------------------------------------------
// Prep: wb[p][oc][ci] = bf16(w[oc][ci][p]) for both conv layers; zero m.
// ---------------------------------------------------------------------------
__global__ __launch_bounds__(256) void prep_kernel(
    const float* __restrict__ w0, const float* __restrict__ wf,
    unsigned short* __restrict__ wb0, unsigned short* __restrict__ wbf,
    float* __restrict__ m)
{
    const int t = blockIdx.x * 256 + threadIdx.x;
    for (int i = t; i < C*C*9; i += 32*256) {
        int p = i % 9; int rest = i / 9; int ci = rest % C; int oc = rest / C;
        wb0[(p*C + oc)*C + ci] = f2bf(w0[i]);
        wbf[(p*C + oc)*C + ci] = f2bf(wf[i]);
    }
    for (int i = t; i < BB*C; i += 32*256) m[i] = 0.f;
}

// ---------------------------------------------------------------------------
// MFMA implicit-GEMM 3x3 conv. Block: 16x16 px tile, all 64 oc, one staging.
// FIRST:  in = x fp32 NCHW  -> out = x0 bf16 NHWC (+bias)
// !FIRST: in = y bf16 NHWC  -> out = fp32 NCHW (+bias+residual x)
// ---------------------------------------------------------------------------
template<bool FIRST>
__global__ __launch_bounds__(256) void conv_mfma_kernel(
    const void* __restrict__ in,
    const unsigned short* __restrict__ wb,   // [9][64][64] bf16 (B^T)
    const float* __restrict__ bias,
    const float* __restrict__ res,
    void* __restrict__ outp)
{
    __shared__ unsigned short tile[NPX*TS];  // 46.7 KB
    const int b  = blockIdx.z;
    const int h0 = blockIdx.y * 16;
    const int w0 = blockIdx.x * 16;
    const int t  = threadIdx.x;

    // ---- stage halo tile as NHWC bf16, zero-padded ----
    {
        const int pxi = t & 31, g = t >> 5;          // g = channel octet
        for (int px = pxi; px < NPX; px += 32) {
            int th = px / 18, tw = px - th*18;
            int gh = h0 + th - 1, gw = w0 + tw - 1;
            short8 v = {0,0,0,0,0,0,0,0};
            if ((unsigned)gh < HH && (unsigned)gw < WW) {
                if (FIRST) {
                    const float* sp = (const float*)in
                        + ((size_t)(b*C + g*8)*HW + gh*WW + gw);
#pragma unroll
                    for (int k = 0; k < 8; ++k) v[k] = (short)f2bf(sp[k*HW]);
                } else {
                    v = *(const short8*)((const unsigned short*)in
                        + ((size_t)(b*HW) + gh*WW + gw)*C + g*8);
                }
            }
            *(short8*)&tile[px*TS + g*8] = v;
        }
    }
    __syncthreads();

    const int wid = t >> 6, ln = t & 63;
    const int l15 = ln & 15, q = ln >> 4;

    f32x4 acc[4][4];
#pragma unroll
    for (int mg = 0; mg < 4; ++mg)
#pragma unroll
        for (int nt = 0; nt < 4; ++nt) acc[mg][nt] = (f32x4){0.f,0.f,0.f,0.f};

    // K-loop: 9 taps x 2 ci-halves, all from the one resident tile (no barriers)
#pragma unroll
    for (int p = 0; p < 9; ++p) {
        const int dh = p / 3, dw = p % 3;
#pragma unroll
        for (int ks = 0; ks < 2; ++ks) {
            short8 bfrag[4];
#pragma unroll
            for (int nt = 0; nt < 4; ++nt)
                bfrag[nt] = *(const short8*)&wb[((size_t)(p*C) + nt*16 + l15)*C + ks*32 + q*8];
            short8 afrag[4];
#pragma unroll
            for (int mg = 0; mg < 4; ++mg) {
                const int r = wid*4 + mg;            // tile row (output row r)
                afrag[mg] = *(const short8*)&tile[((r+dh)*18 + l15 + dw)*TS + ks*32 + q*8];
            }
#pragma unroll
            for (int mg = 0; mg < 4; ++mg)
#pragma unroll
                for (int nt = 0; nt < 4; ++nt)
                    acc[mg][nt] = __builtin_amdgcn_mfma_f32_16x16x32_bf16(
                        afrag[mg], bfrag[nt], acc[mg][nt], 0, 0, 0);
        }
    }

    // ---- epilogue ----
    if (FIRST) {
        unsigned short* x0 = (unsigned short*)outp;
#pragma unroll
        for (int mg = 0; mg < 4; ++mg) {
            const int hh = h0 + wid*4 + mg;
#pragma unroll
            for (int nt = 0; nt < 4; ++nt) {
                const int oc = nt*16 + l15;
                const float bv = bias[oc];
#pragma unroll
                for (int reg = 0; reg < 4; ++reg) {
                    const int wwp = w0 + q*4 + reg;
                    x0[((size_t)(b*HW) + hh*WW + wwp)*C + oc] = f2bf(acc[mg][nt][reg] + bv);
                }
            }
        }
    } else {
        float* outg = (float*)outp;
#pragma unroll
        for (int mg = 0; mg < 4; ++mg) {
            const int hh = h0 + wid*4 + mg;
#pragma unroll
            for (int nt = 0; nt < 4; ++nt) {
                const int oc = nt*16 + l15;
                const float bv = bias[oc];
                const size_t base = (size_t)(b*C + oc)*HW + hh*WW + w0 + q*4;
                const float4 rv = *(const float4*)&res[base];
                float4 ov;
                ov.x = acc[mg][nt][0] + bv + rv.x;
                ov.y = acc[mg][nt][1] + bv + rv.y;
                ov.z = acc[mg][nt][2] + bv + rv.z;
                ov.w = acc[mg][nt][3] + bv + rv.w;
                *(float4*)&outg[base] = ov;
            }
        }
    }
}

// ---------------------------------------------------------------------------
// Per-(b,c) spatial mean of x0 (NHWC bf16). 128 blocks, atomicAdd partials.
// ---------------------------------------------------------------------------
__global__ __launch_bounds__(256) void mean_kernel(
    const unsigned short* __restrict__ x0, float* __restrict__ m)
{
    const int b = blockIdx.x >> 4, slice = blockIdx.x & 15;
    const int t = threadIdx.x;
    const int pxi = t >> 3, g = t & 7;
    const unsigned short* base = x0 + ((size_t)b*HW + slice*1024)*C + g*8;
    float s[8];
#pragma unroll
    for (int k = 0; k < 8; ++k) s[k] = 0.f;
    for (int it = 0; it < 32; ++it) {
        short8 v = *(const short8*)&base[(size_t)(it*32 + pxi)*C];
#pragma unroll
        for (int k = 0; k < 8; ++k) s[k] += bf2f((unsigned short)v[k]);
    }
    __shared__ float red[32][64];
#pragma unroll
    for (int k = 0; k < 8; ++k) red[pxi][g*8+k] = s[k];
    __syncthreads();
    if (t < 64) {
        float acc = 0.f;
        for (int i = 0; i < 32; ++i) acc += red[i][t];
        atomicAdd(&m[b*C + t], acc * (1.f/(float)HW));
    }
}

// ---------------------------------------------------------------------------
// Fused: depthwise3x3 + ECA -> outv[64] regs; fil = w3 @ outv + b3;
// y = leaky(sum_j fil*patch). x0/y NHWC bf16. One staging, LDS-transposed store.
// ---------------------------------------------------------------------------
__global__ __launch_bounds__(256) void fused_kernel(
    const unsigned short* __restrict__ x0,
    const float* __restrict__ w1, const float* __restrict__ b1,
    const float* __restrict__ w2, const float* __restrict__ b2,
    const float* __restrict__ w3, const float* __restrict__ b3,
    const float* __restrict__ m,
    unsigned short* __restrict__ y)
{
    __shared__ unsigned short tile[NPX*TS];   // 46.7 KB
    __shared__ unsigned short ybuf[256*TS];   // 36.9 KB
    const int b  = blockIdx.z;
    const int h0 = blockIdx.y * 16;
    const int w0 = blockIdx.x * 16;
    const int t  = threadIdx.x;

    {
        const int pxi = t & 31, g = t >> 5;
        for (int px = pxi; px < NPX; px += 32) {
            int th = px / 18, tw = px - th*18;
            int gh = h0 + th - 1, gw = w0 + tw - 1;
            short8 v = {0,0,0,0,0,0,0,0};
            if ((unsigned)gh < HH && (unsigned)gw < WW)
                v = *(const short8*)&x0[((size_t)(b*HW) + gh*WW + gw)*C + g*8];
            *(short8*)&tile[px*TS + g*8] = v;
        }
    }
    __syncthreads();

    const int r = t >> 4, cc = t & 15;                 // thread's output pixel
    const unsigned short* tbase = tile + (r*18 + cc)*TS;

    // ---- phase 1: depthwise + attention -> outv[64] ----
    float outv[64];
    const float w2a = w2[0], w2b = w2[1], w2c = w2[2], b2v = b2[0];
#pragma unroll
    for (int g = 0; g < 8; ++g) {
        float dw8[8];
#pragma unroll
        for (int k = 0; k < 8; ++k) dw8[k] = 0.f;
#pragma unroll
        for (int j = 0; j < 9; ++j) {
            short8 v = *(const short8*)&tbase[((j/3)*18 + (j%3))*TS + g*8];
#pragma unroll
            for (int k = 0; k < 8; ++k)
                dw8[k] = fmaf(w1[(g*8+k)*9 + j], bf2f((unsigned short)v[k]), dw8[k]);
        }
#pragma unroll
        for (int k = 0; k < 8; ++k) {
            const int c = g*8 + k;
            const float mc = m[b*C + c];
            const float mp = (c > 0)  ? m[b*C + c - 1] : 0.f;
            const float mn = (c < 63) ? m[b*C + c + 1] : 0.f;
            outv[c] = dw8[k] + b1[c] + fmaf(w2a, mp, fmaf(w2b, mc, fmaf(w2c, mn, b2v)));
        }
    }

    // ---- phase 2: dynamic filters + dynamic conv + leaky ----
    for (int c = 0; c < 64; ++c) {
        const float* w3p = w3 + c*9*64;                // uniform -> s_load
        float f[9];
#pragma unroll
        for (int j = 0; j < 9; ++j) f[j] = b3[c*9 + j];
#pragma unroll
        for (int ci = 0; ci < 64; ++ci)                // 9 independent chains
#pragma unroll
            for (int j = 0; j < 9; ++j)
                f[j] = fmaf(w3p[j*64 + ci], outv[ci], f[j]);
        float yc = 0.f;
#pragma unroll
        for (int j = 0; j < 9; ++j)
            yc = fmaf(f[j], bf2f(tbase[((j/3)*18 + (j%3))*TS + c]), yc);
        yc = (yc >= 0.f) ? yc : 0.2f * yc;
        ybuf[t*TS + c] = f2bf(yc);
    }
    __syncthreads();

    // ---- coalesced NHWC writeout via LDS transpose buffer ----
    for (int id = t; id < 2048; id += 256) {
        int px = id >> 3, g = id & 7;
        short8 v = *(const short8*)&ybuf[px*TS + g*8];
        int rr = px >> 4, cw = px & 15;
        *(short8*)&y[((size_t)(b*HW) + (h0+rr)*WW + (w0+cw))*C + g*8] = v;
    }
}

extern "C" void kernel_launch(void* const* d_in, const int* in_sizes, int n_in,
                              void* d_out, int out_size, void* d_ws, size_t ws_size,
                              hipStream_t stream) {
    const float* x  = (const float*)d_in[0];
    const float* w0 = (const float*)d_in[1];
    const float* b0 = (const float*)d_in[2];
    const float* w1 = (const float*)d_in[3];
    const float* b1 = (const float*)d_in[4];
    const float* w2 = (const float*)d_in[5];
    const float* b2 = (const float*)d_in[6];
    const float* w3 = (const float*)d_in[7];
    const float* b3 = (const float*)d_in[8];
    const float* wf = (const float*)d_in[9];
    const float* bf = (const float*)d_in[10];
    float* out = (float*)d_out;

    unsigned short* x0  = (unsigned short*)d_ws;            // [B,H,W,C] bf16
    unsigned short* y   = x0 + (size_t)BB*HW*C;             // [B,H,W,C] bf16
    float*          m   = (float*)(y + (size_t)BB*HW*C);    // [B*C]
    unsigned short* wb0 = (unsigned short*)(m + BB*C);      // [9][64][64] bf16
    unsigned short* wbf = wb0 + 9*C*C;

    prep_kernel<<<32, 256, 0, stream>>>(w0, wf, wb0, wbf, m);
    conv_mfma_kernel<true><<<dim3(8,8,8), 256, 0, stream>>>(x, wb0, b0, nullptr, x0);
    mean_kernel<<<128, 256, 0, stream>>>(x0, m);
    fused_kernel<<<dim3(8,8,8), 256, 0, stream>>>(x0, w1, b1, w2, b2, w3, b3, m, y);
    conv_mfma_kernel<false><<<dim3(8,8,8), 256, 0, stream>>>(y, wbf, bf, x, out);
}

// Round 4
// 223.620 us; speedup vs baseline: 5.1899x; 2.4266x over previous
//
#include <hip/hip_runtime.h>

#define BB 8
#define C 64
#define HH 128
#define WW 128
#define HW (HH*WW)

#define TS 72        // LDS channel stride (ushorts) for halo tile
#define NPX 324      // 18*18 halo tile pixels

typedef __attribute__((ext_vector_type(8))) short short8;
typedef __attribute__((ext_vector_type(4))) float f32x4;

__device__ inline unsigned short f2bf(float f) {
    union { float f; unsigned u; } v; v.f = f;
    unsigned r = v.u + 0x7fff + ((v.u >> 16) & 1);   // RNE
    return (unsigned short)(r >> 16);
}
__device__ inline float bf2f(unsigned short h) {
    union { unsigned u; float f; } v; v.u = ((unsigned)h) << 16;
    return v.f;
}

// ---------------------------------------------------------------------------
// Prep: wb[p][oc][ci] (B^T bf16) for conv0/convf; wb3[j][oc][k] (B^T bf16) and
// b3r[j][oc] for the dynamic-filter GEMM; zero m.
// ---------------------------------------------------------------------------
__global__ __launch_bounds__(256) void prep_kernel(
    const float* __restrict__ w0, const float* __restrict__ wf,
    const float* __restrict__ w3, const float* __restrict__ b3,
    unsigned short* __restrict__ wb0, unsigned short* __restrict__ wbf,
    unsigned short* __restrict__ wb3, float* __restrict__ b3r,
    float* __restrict__ m)
{
    const int t = blockIdx.x * 256 + threadIdx.x;
    for (int i = t; i < C*C*9; i += 32*256) {
        int p = i % 9; int rest = i / 9; int ci = rest % C; int oc = rest / C;
        wb0[(p*C + oc)*C + ci] = f2bf(w0[i]);
        wbf[(p*C + oc)*C + ci] = f2bf(wf[i]);
    }
    for (int i = t; i < 9*C*C; i += 32*256) {        // dst index: ((j*64+oc)*64+k)
        int j = i >> 12, oc = (i >> 6) & 63, k = i & 63;
        wb3[i] = f2bf(w3[(oc*9 + j)*C + k]);
    }
    for (int i = t; i < 9*C; i += 32*256) {          // b3r[j*64+oc] = b3[oc*9+j]
        int j = i >> 6, oc = i & 63;
        b3r[i] = b3[oc*9 + j];
    }
    for (int i = t; i < BB*C; i += 32*256) m[i] = 0.f;
}

// ---------------------------------------------------------------------------
// MFMA implicit-GEMM 3x3 conv. Block: 16x16 px tile, all 64 oc, one staging.
// FIRST:  in = x fp32 NCHW  -> out = x0 bf16 NHWC (+bias)
// !FIRST: in = y bf16 NHWC  -> out = fp32 NCHW (+bias+residual x)
// ---------------------------------------------------------------------------
template<bool FIRST>
__global__ __launch_bounds__(256) void conv_mfma_kernel(
    const void* __restrict__ in,
    const unsigned short* __restrict__ wb,   // [9][64][64] bf16 (B^T)
    const float* __restrict__ bias,
    const float* __restrict__ res,
    void* __restrict__ outp)
{
    __shared__ unsigned short tile[NPX*TS];  // 46.7 KB
    const int b  = blockIdx.z;
    const int h0 = blockIdx.y * 16;
    const int w0 = blockIdx.x * 16;
    const int t  = threadIdx.x;

    {
        const int pxi = t & 31, g = t >> 5;          // g = channel octet
        for (int px = pxi; px < NPX; px += 32) {
            int th = px / 18, tw = px - th*18;
            int gh = h0 + th - 1, gw = w0 + tw - 1;
            short8 v = {0,0,0,0,0,0,0,0};
            if ((unsigned)gh < HH && (unsigned)gw < WW) {
                if (FIRST) {
                    const float* sp = (const float*)in
                        + ((size_t)(b*C + g*8)*HW + gh*WW + gw);
#pragma unroll
                    for (int k = 0; k < 8; ++k) v[k] = (short)f2bf(sp[k*HW]);
                } else {
                    v = *(const short8*)((const unsigned short*)in
                        + ((size_t)(b*HW) + gh*WW + gw)*C + g*8);
                }
            }
            *(short8*)&tile[px*TS + g*8] = v;
        }
    }
    __syncthreads();

    const int wid = t >> 6, ln = t & 63;
    const int l15 = ln & 15, q = ln >> 4;

    f32x4 acc[4][4];
#pragma unroll
    for (int mg = 0; mg < 4; ++mg)
#pragma unroll
        for (int nt = 0; nt < 4; ++nt) acc[mg][nt] = (f32x4){0.f,0.f,0.f,0.f};

#pragma unroll
    for (int p = 0; p < 9; ++p) {
        const int dh = p / 3, dw = p % 3;
#pragma unroll
        for (int ks = 0; ks < 2; ++ks) {
            short8 bfrag[4];
#pragma unroll
            for (int nt = 0; nt < 4; ++nt)
                bfrag[nt] = *(const short8*)&wb[((size_t)(p*C) + nt*16 + l15)*C + ks*32 + q*8];
            short8 afrag[4];
#pragma unroll
            for (int mg = 0; mg < 4; ++mg) {
                const int r = wid*4 + mg;
                afrag[mg] = *(const short8*)&tile[((r+dh)*18 + l15 + dw)*TS + ks*32 + q*8];
            }
#pragma unroll
            for (int mg = 0; mg < 4; ++mg)
#pragma unroll
                for (int nt = 0; nt < 4; ++nt)
                    acc[mg][nt] = __builtin_amdgcn_mfma_f32_16x16x32_bf16(
                        afrag[mg], bfrag[nt], acc[mg][nt], 0, 0, 0);
        }
    }

    if (FIRST) {
        unsigned short* x0 = (unsigned short*)outp;
#pragma unroll
        for (int mg = 0; mg < 4; ++mg) {
            const int hh = h0 + wid*4 + mg;
#pragma unroll
            for (int nt = 0; nt < 4; ++nt) {
                const int oc = nt*16 + l15;
                const float bv = bias[oc];
#pragma unroll
                for (int reg = 0; reg < 4; ++reg) {
                    const int wwp = w0 + q*4 + reg;
                    x0[((size_t)(b*HW) + hh*WW + wwp)*C + oc] = f2bf(acc[mg][nt][reg] + bv);
                }
            }
        }
    } else {
        float* outg = (float*)outp;
#pragma unroll
        for (int mg = 0; mg < 4; ++mg) {
            const int hh = h0 + wid*4 + mg;
#pragma unroll
            for (int nt = 0; nt < 4; ++nt) {
                const int oc = nt*16 + l15;
                const float bv = bias[oc];
                const size_t base = (size_t)(b*C + oc)*HW + hh*WW + w0 + q*4;
                const float4 rv = *(const float4*)&res[base];
                float4 ov;
                ov.x = acc[mg][nt][0] + bv + rv.x;
                ov.y = acc[mg][nt][1] + bv + rv.y;
                ov.z = acc[mg][nt][2] + bv + rv.z;
                ov.w = acc[mg][nt][3] + bv + rv.w;
                *(float4*)&outg[base] = ov;
            }
        }
    }
}

// ---------------------------------------------------------------------------
// Per-(b,c) spatial mean of x0 (NHWC bf16). 128 blocks, atomicAdd partials.
// ---------------------------------------------------------------------------
__global__ __launch_bounds__(256) void mean_kernel(
    const unsigned short* __restrict__ x0, float* __restrict__ m)
{
    const int b = blockIdx.x >> 4, slice = blockIdx.x & 15;
    const int t = threadIdx.x;
    const int pxi = t >> 3, g = t & 7;
    const unsigned short* base = x0 + ((size_t)b*HW + slice*1024)*C + g*8;
    float s[8];
#pragma unroll
    for (int k = 0; k < 8; ++k) s[k] = 0.f;
    for (int it = 0; it < 32; ++it) {
        short8 v = *(const short8*)&base[(size_t)(it*32 + pxi)*C];
#pragma unroll
        for (int k = 0; k < 8; ++k) s[k] += bf2f((unsigned short)v[k]);
    }
    __shared__ float red[32][64];
#pragma unroll
    for (int k = 0; k < 8; ++k) red[pxi][g*8+k] = s[k];
    __syncthreads();
    if (t < 64) {
        float acc = 0.f;
        for (int i = 0; i < 32; ++i) acc += red[i][t];
        atomicAdd(&m[b*C + t], acc * (1.f/(float)HW));
    }
}

// ---------------------------------------------------------------------------
// Fused: depthwise3x3 + ECA -> outv[64] -> LDS A-matrix (bf16, XOR-swizzled);
// fil via MFMA (A[256x64] x wb3^T[576x64], n reordered as j*64+oc so each
// 16-wide n-tile has uniform tap j); dynamic-conv consume from resident tile;
// leaky; ybuf (reusing A region) -> coalesced NHWC bf16 store.
// LDS total 79.4 KB -> 2 blocks/CU.
// ---------------------------------------------------------------------------
__global__ __launch_bounds__(256) void fused_kernel(
    const unsigned short* __restrict__ x0,
    const float* __restrict__ w1, const float* __restrict__ b1,
    const float* __restrict__ w2, const float* __restrict__ b2,
    const unsigned short* __restrict__ wb3,  // [9][64][64] bf16 (B^T, n'=j*64+oc)
    const float* __restrict__ b3r,           // [9][64]
    const float* __restrict__ m,
    unsigned short* __restrict__ y)
{
    __shared__ unsigned short tile[NPX*TS];   // 46656 B
    __shared__ unsigned short alds[256*64];   // 32768 B; reused as ybuf
    const int b  = blockIdx.z;
    const int h0 = blockIdx.y * 16;
    const int w0 = blockIdx.x * 16;
    const int t  = threadIdx.x;

    {
        const int pxi = t & 31, g = t >> 5;
        for (int px = pxi; px < NPX; px += 32) {
            int th = px / 18, tw = px - th*18;
            int gh = h0 + th - 1, gw = w0 + tw - 1;
            short8 v = {0,0,0,0,0,0,0,0};
            if ((unsigned)gh < HH && (unsigned)gw < WW)
                v = *(const short8*)&x0[((size_t)(b*HW) + gh*WW + gw)*C + g*8];
            *(short8*)&tile[px*TS + g*8] = v;
        }
    }
    __syncthreads();

    const int r = t >> 4, cc = t & 15;
    const unsigned short* tbase = tile + (r*18 + cc)*TS;

    // ---- phase 1: depthwise + attention -> outv[64] ----
    float outv[64];
    const float w2a = w2[0], w2b = w2[1], w2c = w2[2], b2v = b2[0];
#pragma unroll
    for (int g = 0; g < 8; ++g) {
        float dw8[8];
#pragma unroll
        for (int k = 0; k < 8; ++k) dw8[k] = 0.f;
#pragma unroll
        for (int j = 0; j < 9; ++j) {
            short8 v = *(const short8*)&tbase[((j/3)*18 + (j%3))*TS + g*8];
#pragma unroll
            for (int k = 0; k < 8; ++k)
                dw8[k] = fmaf(w1[(g*8+k)*9 + j], bf2f((unsigned short)v[k]), dw8[k]);
        }
#pragma unroll
        for (int k = 0; k < 8; ++k) {
            const int c = g*8 + k;
            const float mc = m[b*C + c];
            const float mp = (c > 0)  ? m[b*C + c - 1] : 0.f;
            const float mn = (c < 63) ? m[b*C + c + 1] : 0.f;
            outv[c] = dw8[k] + b1[c] + fmaf(w2a, mp, fmaf(w2b, mc, fmaf(w2c, mn, b2v)));
        }
    }

    // ---- write A[px][k] bf16 to LDS, XOR-swizzled 16B groups ----
    {
        const int sw = t & 7;
#pragma unroll
        for (int g = 0; g < 8; ++g) {
            short8 v;
#pragma unroll
            for (int k = 0; k < 8; ++k) v[k] = (short)f2bf(outv[g*8 + k]);
            *(short8*)&alds[t*64 + ((g ^ sw) * 8)] = v;
        }
    }
    __syncthreads();

    const int wid = t >> 6, ln = t & 63;
    const int l15 = ln & 15, q = ln >> 4;

    // ---- preload a-frags once (reused across all 36 n-tiles) ----
    short8 afrag[4][2];
#pragma unroll
    for (int mg = 0; mg < 4; ++mg) {
        const int px = (wid*4 + mg)*16 + l15;
        const int sw = px & 7;
#pragma unroll
        for (int ks = 0; ks < 2; ++ks)
            afrag[mg][ks] = *(const short8*)&alds[px*64 + (((ks*4 + q) ^ sw) * 8)];
    }

    f32x4 y_acc[4][4];   // [mg][ntoc]
#pragma unroll
    for (int mg = 0; mg < 4; ++mg)
#pragma unroll
        for (int nt = 0; nt < 4; ++nt) y_acc[mg][nt] = (f32x4){0.f,0.f,0.f,0.f};

    // ---- phase 2: 36 n-tiles (9 taps x 4 oc-groups) ----
#pragma unroll
    for (int j = 0; j < 9; ++j) {
        const int dh = j / 3, dw = j % 3;
#pragma unroll
        for (int ntoc = 0; ntoc < 4; ++ntoc) {
            const int oc = ntoc*16 + l15;
            const float b3v = b3r[j*64 + oc];
            const short8 bf0 = *(const short8*)&wb3[((size_t)(j*64 + oc))*64 + q*8];
            const short8 bf1 = *(const short8*)&wb3[((size_t)(j*64 + oc))*64 + 32 + q*8];
            f32x4 fil[4];
#pragma unroll
            for (int mg = 0; mg < 4; ++mg) {
                f32x4 a = (f32x4){b3v, b3v, b3v, b3v};
                a = __builtin_amdgcn_mfma_f32_16x16x32_bf16(afrag[mg][0], bf0, a, 0, 0, 0);
                a = __builtin_amdgcn_mfma_f32_16x16x32_bf16(afrag[mg][1], bf1, a, 0, 0, 0);
                fil[mg] = a;
            }
#pragma unroll
            for (int mg = 0; mg < 4; ++mg) {
                const int rr = wid*4 + mg;
                const unsigned short* pb = &tile[((rr+dh)*18 + q*4 + dw)*TS + oc];
#pragma unroll
                for (int reg = 0; reg < 4; ++reg) {
                    const float pv = bf2f(pb[reg*TS]);
                    y_acc[mg][ntoc][reg] = fmaf(fil[mg][reg], pv, y_acc[mg][ntoc][reg]);
                }
            }
        }
    }

    // ---- leaky + ybuf (reuse alds) + coalesced NHWC writeout ----
    __syncthreads();                          // all alds reads done
    unsigned short* ybuf = alds;
#pragma unroll
    for (int mg = 0; mg < 4; ++mg) {
        const int rr = wid*4 + mg;
#pragma unroll
        for (int ntoc = 0; ntoc < 4; ++ntoc) {
            const int oc = ntoc*16 + l15;
#pragma unroll
            for (int reg = 0; reg < 4; ++reg) {
                float v = y_acc[mg][ntoc][reg];
                v = (v >= 0.f) ? v : 0.2f * v;
                ybuf[(rr*16 + q*4 + reg)*64 + oc] = f2bf(v);
            }
        }
    }
    __syncthreads();
    for (int id = t; id < 2048; id += 256) {
        int px = id >> 3, g = id & 7;
        short8 v = *(const short8*)&ybuf[px*64 + g*8];
        int rr = px >> 4, cw = px & 15;
        *(short8*)&y[((size_t)(b*HW) + (h0+rr)*WW + (w0+cw))*C + g*8] = v;
    }
}

extern "C" void kernel_launch(void* const* d_in, const int* in_sizes, int n_in,
                              void* d_out, int out_size, void* d_ws, size_t ws_size,
                              hipStream_t stream) {
    const float* x  = (const float*)d_in[0];
    const float* w0 = (const float*)d_in[1];
    const float* b0 = (const float*)d_in[2];
    const float* w1 = (const float*)d_in[3];
    const float* b1 = (const float*)d_in[4];
    const float* w2 = (const float*)d_in[5];
    const float* b2 = (const float*)d_in[6];
    const float* w3 = (const float*)d_in[7];
    const float* b3 = (const float*)d_in[8];
    const float* wf = (const float*)d_in[9];
    const float* bf = (const float*)d_in[10];
    float* out = (float*)d_out;

    unsigned short* x0  = (unsigned short*)d_ws;            // [B,H,W,C] bf16
    unsigned short* y   = x0 + (size_t)BB*HW*C;             // [B,H,W,C] bf16
    float*          m   = (float*)(y + (size_t)BB*HW*C);    // [B*C]
    unsigned short* wb0 = (unsigned short*)(m + BB*C);      // [9][64][64] bf16
    unsigned short* wbf = wb0 + 9*C*C;
    unsigned short* wb3 = wbf + 9*C*C;                      // [9][64][64] bf16
    float*          b3r = (float*)(wb3 + 9*C*C);            // [9][64]

    prep_kernel<<<32, 256, 0, stream>>>(w0, wf, w3, b3, wb0, wbf, wb3, b3r, m);
    conv_mfma_kernel<true><<<dim3(8,8,8), 256, 0, stream>>>(x, wb0, b0, nullptr, x0);
    mean_kernel<<<128, 256, 0, stream>>>(x0, m);
    fused_kernel<<<dim3(8,8,8), 256, 0, stream>>>(x0, w1, b1, w2, b2, wb3, b3r, m, y);
    conv_mfma_kernel<false><<<dim3(8,8,8), 256, 0, stream>>>(y, wbf, bf, x, out);
}